// Round 4
// baseline (97.675 us; speedup 1.0000x reference)
//
#include <hip/hip_runtime.h>
#include <hip/hip_bf16.h>

#define BB 8
#define FF 4096
#define SS 1024
#define DD 128
#define DLL 256
#define NF (BB*FF)     // 32768 facts
#define NNODE (BB*SS)  // 8192 (b,s) rows
#define FPB 32         // facts per msg block (64 messages)

typedef short  short8 __attribute__((ext_vector_type(8)));
typedef float  f32x4  __attribute__((ext_vector_type(4)));

__device__ __forceinline__ ushort f2bf(float x) {
    uint u = __float_as_uint(x);
    uint r = (u + 0x7fffu + ((u >> 16) & 1u)) >> 16;
    return (ushort)r;
}
__device__ __forceinline__ float bf2f(uint lo16) {
    return __uint_as_float(lo16 << 16);
}

// gelu(x) = 0.5x(1+erf(x/sqrt2)); erf via A&S 7.1.26, |err|<=1.5e-7, branchless.
__device__ __forceinline__ float gelu_fast(float x) {
    const float z = fabsf(x) * 0.70710678118654752440f;
    const float t = __builtin_amdgcn_rcpf(__builtin_fmaf(0.3275911f, z, 1.0f));
    float p = 1.061405429f;
    p = __builtin_fmaf(p, t, -1.453152027f);
    p = __builtin_fmaf(p, t, 1.421413741f);
    p = __builtin_fmaf(p, t, -0.284496736f);
    p = __builtin_fmaf(p, t, 0.254829592f);
    p *= t;
    const float e = __expf(-z * z);
    const float erfv = __builtin_fmaf(-p, e, 1.0f);   // erf(|x|/sqrt2)
    return 0.5f * x * (1.0f + copysignf(erfv, x));
}

__device__ __forceinline__ void pk_add_bf16(ushort* ap, uint packed) {
    asm volatile("global_atomic_pk_add_bf16 %0, %1, off"
                 :: "v"((unsigned long long)(uintptr_t)ap), "v"(packed) : "memory");
}

// ---------------------------------------------------------------------------
// Prep: bf16 embeddings; bf16 w1T[256][384], w2T[128][256].
// ---------------------------------------------------------------------------
#define N_POS   (SS*DD)
#define N_PRED_ (14*DD)
#define N_W1    (384*256)
#define N_W2    (256*128)
#define N_PREP  (N_POS + N_PRED_ + N_W1 + N_W2)

__global__ __launch_bounds__(256) void prep_kernel(
    const float* __restrict__ pos, const float* __restrict__ pred,
    const float* __restrict__ w1,  const float* __restrict__ w2,
    ushort* __restrict__ pos_bf, ushort* __restrict__ pred_bf,
    ushort* __restrict__ w1T,    ushort* __restrict__ w2T)
{
    int i = blockIdx.x * 256 + threadIdx.x;
    if (i < N_POS) { pos_bf[i] = f2bf(pos[i]); return; }
    i -= N_POS;
    if (i < N_PRED_) { pred_bf[i] = f2bf(pred[i]); return; }
    i -= N_PRED_;
    if (i < N_W1) { int k = i >> 8, n = i & 255; w1T[n*384 + k] = f2bf(w1[i]); return; }
    i -= N_W1;
    if (i < N_W2) { int k = i >> 7, d = i & 127; w2T[d*256 + k] = f2bf(w2[i]); return; }
}

// ---------------------------------------------------------------------------
// msg kernel (MFMA, swapped operands -> outputs indexed [n][m]/[d][m]).
// Epilogue: packed-bf16 hardware atomic scatter into aggbf[node][128].
// LDS = exactly 32 KB -> 5 blocks/CU.
// ---------------------------------------------------------------------------
__global__ __launch_bounds__(256) void msg_kernel(
    const int* __restrict__ a0, const int* __restrict__ a1,
    const int* __restrict__ pidx, const float* __restrict__ bidir,
    const ushort* __restrict__ pos_bf, const ushort* __restrict__ pred_bf,
    const ushort* __restrict__ w1T, const float* __restrict__ b1,
    const ushort* __restrict__ w2T, const float* __restrict__ b2,
    ushort* __restrict__ aggbf)
{
    __shared__ uint4 shm[2048];           // union: xs (1536 u4) / h1 (2048 u4)

    const int tid = threadIdx.x;
    const int fbase = blockIdx.x * FPB;
    const int wid = tid >> 6, lane = tid & 63;
    const int lq = lane >> 4, lr = lane & 15;
    const int factL = lr >> 1, par = lr & 1;

    // ---- stage gathered inputs (bf16, 16B units, XOR-swizzled by fact&7) ----
    #pragma unroll
    for (int it = 0; it < 6; ++it) {
        const int U = tid + it * 256;
        const int f = U / 48, u = U - 48 * f;
        const int seg = u >> 4, du = u & 15;
        const int g = fbase + f;
        const int row = (seg == 0) ? a0[g] : ((seg == 1) ? pidx[g] : a1[g]);
        const uint4* src = (const uint4*)(((seg == 1) ? pred_bf : pos_bf) + row * DD) + du;
        shm[f * 48 + (u ^ (f & 7))] = *src;
    }
    __syncthreads();

    // ---- GEMM1: D1[n][m], acc[nf][mf] ----
    f32x4 acc[4][4];
    #pragma unroll
    for (int nf = 0; nf < 4; ++nf)
        #pragma unroll
        for (int mf = 0; mf < 4; ++mf) acc[nf][mf] = (f32x4)0.0f;

    for (int ks = 0; ks < 12; ++ks) {
        const int k_el = ks * 32 + lq * 8;
        const int seg = ks >> 2;
        const int kp = k_el + (par ? (seg == 0 ? 256 : (seg == 2 ? -256 : 0)) : 0);
        const int uq = (kp >> 3) ^ factL;
        short8 xfrag[4];
        #pragma unroll
        for (int mf = 0; mf < 4; ++mf)
            xfrag[mf] = *(const short8*)&shm[(mf * 8 + factL) * 48 + uq];
        short8 wfrag[4];
        #pragma unroll
        for (int nf = 0; nf < 4; ++nf)
            wfrag[nf] = *(const short8*)(w1T + (wid * 64 + nf * 16 + lr) * 384 + k_el);
        #pragma unroll
        for (int nf = 0; nf < 4; ++nf)
            #pragma unroll
            for (int mf = 0; mf < 4; ++mf)
                acc[nf][mf] = __builtin_amdgcn_mfma_f32_16x16x32_bf16(wfrag[nf], xfrag[mf], acc[nf][mf], 0, 0, 0);
    }
    __syncthreads();   // xs dead; reuse LDS as h1[64][256] bf16 (swizzled)

    // ---- bias + gelu + packed h1 store (ds_write_b64) ----
    #pragma unroll
    for (int nf = 0; nf < 4; ++nf) {
        const float4 bj = *(const float4*)(b1 + wid * 64 + nf * 16 + lq * 4);
        #pragma unroll
        for (int mf = 0; mf < 4; ++mf) {
            const int m = mf * 16 + lr;
            uint2 t;
            t.x = (uint)f2bf(gelu_fast(acc[nf][mf][0] + bj.x)) |
                  ((uint)f2bf(gelu_fast(acc[nf][mf][1] + bj.y)) << 16);
            t.y = (uint)f2bf(gelu_fast(acc[nf][mf][2] + bj.z)) |
                  ((uint)f2bf(gelu_fast(acc[nf][mf][3] + bj.w)) << 16);
            const int col = wid * 128 + nf * 32 + lq * 8;   // byte col
            const int byteoff = m * 512 + (((col >> 4) ^ (m & 15)) << 4) + (col & 15);
            *(uint2*)((char*)shm + byteoff) = t;
        }
    }
    __syncthreads();

    // ---- GEMM2: D2[d][m], acc2[nf][mf] ----
    f32x4 acc2[2][4];
    #pragma unroll
    for (int nf = 0; nf < 2; ++nf)
        #pragma unroll
        for (int mf = 0; mf < 4; ++mf) acc2[nf][mf] = (f32x4)0.0f;

    for (int ks = 0; ks < 8; ++ks) {
        short8 hfrag[4];
        #pragma unroll
        for (int mf = 0; mf < 4; ++mf) {
            const int m = mf * 16 + lr;
            hfrag[mf] = *(const short8*)((char*)shm + m * 512 + ((((ks * 4 + lq)) ^ (m & 15)) << 4));
        }
        short8 w2frag[2];
        #pragma unroll
        for (int nf = 0; nf < 2; ++nf)
            w2frag[nf] = *(const short8*)(w2T + (wid * 32 + nf * 16 + lr) * 256 + ks * 32 + lq * 8);
        #pragma unroll
        for (int nf = 0; nf < 2; ++nf)
            #pragma unroll
            for (int mf = 0; mf < 4; ++mf)
                acc2[nf][mf] = __builtin_amdgcn_mfma_f32_16x16x32_bf16(w2frag[nf], hfrag[mf], acc2[nf][mf], 0, 0, 0);
    }

    // ---- epilogue: bias, bidir weight, packed bf16 atomic scatter ----
    int   node_[4];
    float wgt_[4];
    #pragma unroll
    for (int mf = 0; mf < 4; ++mf) {
        const int g = fbase + mf * 8 + factL;
        wgt_[mf]  = par ? bidir[g] : 1.0f;
        node_[mf] = par ? a0[g] : a1[g];
    }
    const int bidx = fbase >> 12;

    #pragma unroll
    for (int nf = 0; nf < 2; ++nf) {
        const float4 bd = *(const float4*)(b2 + wid * 32 + nf * 16 + lq * 4);
        const int d0 = wid * 32 + nf * 16 + lq * 4;
        #pragma unroll
        for (int mf = 0; mf < 4; ++mf) {
            const float w = wgt_[mf];
            if (w != 0.0f) {
                const float v0 = (acc2[nf][mf][0] + bd.x) * w;
                const float v1 = (acc2[nf][mf][1] + bd.y) * w;
                const float v2 = (acc2[nf][mf][2] + bd.z) * w;
                const float v3 = (acc2[nf][mf][3] + bd.w) * w;
                ushort* ap = aggbf + (size_t)((bidx << 10) + node_[mf]) * DD + d0;
                pk_add_bf16(ap,     (uint)f2bf(v0) | ((uint)f2bf(v1) << 16));
                pk_add_bf16(ap + 2, (uint)f2bf(v2) | ((uint)f2bf(v3) << 16));
            }
        }
    }
}

// ---------------------------------------------------------------------------
// h = pos_emb + aggbf -> LayerNorm -> pooled sums per (b,d).
// One wave per node, 4 nodes per wave.
// ---------------------------------------------------------------------------
#define NPW 4
__global__ __launch_bounds__(256) void ln_pool_kernel(
    const float* __restrict__ pos_emb, const ushort* __restrict__ aggbf,
    const float* __restrict__ ln_g, const float* __restrict__ ln_b,
    float* __restrict__ pooled)
{
    const int wave = threadIdx.x >> 6, lane = threadIdx.x & 63;
    const int nid0 = blockIdx.x * (4 * NPW) + wave * NPW;
    const int b = nid0 >> 10;
    const float2 g2  = *(const float2*)(ln_g + 2 * lane);
    const float2 bb2 = *(const float2*)(ln_b + 2 * lane);
    float p0 = 0.0f, p1 = 0.0f;

    for (int i = 0; i < NPW; ++i) {
        const int nid = nid0 + i;
        const int s = nid & (SS - 1);
        float2 h = *(const float2*)(pos_emb + s * DD + 2 * lane);
        const uint u = *(const uint*)(aggbf + (size_t)nid * DD + 2 * lane);
        h.x += bf2f(u & 0xffffu);
        h.y += bf2f(u >> 16);

        float sum = h.x + h.y;
        #pragma unroll
        for (int o = 32; o > 0; o >>= 1) sum += __shfl_xor(sum, o);
        const float mu = sum * (1.0f / 128.0f);
        const float d0 = h.x - mu, d1 = h.y - mu;
        float sq = d0 * d0 + d1 * d1;
        #pragma unroll
        for (int o = 32; o > 0; o >>= 1) sq += __shfl_xor(sq, o);
        const float rstd = rsqrtf(sq * (1.0f / 128.0f) + 1e-5f);
        p0 += d0 * rstd * g2.x + bb2.x;
        p1 += d1 * rstd * g2.y + bb2.y;
    }

    __shared__ float red[4][128];
    red[wave][2 * lane]     = p0;
    red[wave][2 * lane + 1] = p1;
    __syncthreads();
    if (threadIdx.x < 128) {
        const float v = red[0][threadIdx.x] + red[1][threadIdx.x]
                      + red[2][threadIdx.x] + red[3][threadIdx.x];
        atomicAdd(&pooled[b * DD + threadIdx.x], v);
    }
}

// ---------------------------------------------------------------------------
// Latent head
// ---------------------------------------------------------------------------
__global__ __launch_bounds__(256) void head_kernel(
    const float* __restrict__ pooled,
    const float* __restrict__ lw1, const float* __restrict__ lb1,
    const float* __restrict__ lw2, const float* __restrict__ lb2,
    float* __restrict__ out)
{
    const int b = blockIdx.x;
    const int j = threadIdx.x;
    __shared__ float p[128];
    __shared__ float t1[256];
    if (j < 128) p[j] = pooled[b*DD + j] * (1.0f / (float)SS);
    __syncthreads();
    float acc = lb1[j];
    for (int k = 0; k < 128; ++k) acc += p[k] * lw1[k*256 + j];
    t1[j] = gelu_fast(acc);
    __syncthreads();
    float acc2 = lb2[j];
    for (int k = 0; k < 256; ++k) acc2 += t1[k] * lw2[k*256 + j];
    out[b*DLL + j] = acc2;
}

extern "C" void kernel_launch(void* const* d_in, const int* in_sizes, int n_in,
                              void* d_out, int out_size, void* d_ws, size_t ws_size,
                              hipStream_t stream) {
    const int*   a0       = (const int*)d_in[0];
    const int*   a1       = (const int*)d_in[1];
    const int*   pidx     = (const int*)d_in[2];
    const float* bidir    = (const float*)d_in[3];
    const float* pos_emb  = (const float*)d_in[4];
    const float* pred_emb = (const float*)d_in[5];
    const float* w1       = (const float*)d_in[6];
    const float* b1       = (const float*)d_in[7];
    const float* w2       = (const float*)d_in[8];
    const float* b2       = (const float*)d_in[9];
    const float* ln_g     = (const float*)d_in[10];
    const float* ln_b     = (const float*)d_in[11];
    const float* lw1      = (const float*)d_in[12];
    const float* lb1      = (const float*)d_in[13];
    const float* lw2      = (const float*)d_in[14];
    const float* lb2      = (const float*)d_in[15];

    char* ws = (char*)d_ws;
    const size_t O_AGG  = 0;                 // NNODE*128 bf16 = 2 MB
    const size_t O_POOL = 2097152;           // 4 KB fp32
    const size_t O_PBF  = O_POOL + 4096;     // 256 KB
    const size_t O_PRBF = O_PBF + 262144;    // 3.5 KB
    const size_t O_W1T  = O_PRBF + 3584;     // 192 KB
    const size_t O_W2T  = O_W1T + 196608;    // 64 KB

    ushort* aggbf  = (ushort*)(ws + O_AGG);
    float*  pooled = (float*)(ws + O_POOL);
    ushort* pos_bf = (ushort*)(ws + O_PBF);
    ushort* pred_bf= (ushort*)(ws + O_PRBF);
    ushort* w1T    = (ushort*)(ws + O_W1T);
    ushort* w2T    = (ushort*)(ws + O_W2T);

    hipMemsetAsync(ws, 0, O_POOL + 4096, stream);   // aggbf (bf16 zeros) + pooled
    prep_kernel<<<(N_PREP + 255)/256, 256, 0, stream>>>(
        pos_emb, pred_emb, w1, w2, pos_bf, pred_bf, w1T, w2T);
    msg_kernel<<<NF/FPB, 256, 0, stream>>>(a0, a1, pidx, bidir,
        pos_bf, pred_bf, w1T, b1, w2T, b2, aggbf);
    ln_pool_kernel<<<NNODE/(4*NPW), 256, 0, stream>>>(
        pos_emb, aggbf, ln_g, ln_b, pooled);
    head_kernel<<<BB, 256, 0, stream>>>(pooled, lw1, lb1, lw2, lb2, (float*)d_out);
}

// Round 5
// 79.946 us; speedup vs baseline: 1.2218x; 1.2218x over previous
//
#include <hip/hip_runtime.h>
#include <hip/hip_bf16.h>

#define BB 8
#define FF 4096
#define SS 1024
#define DD 128
#define DLL 256
#define NF (BB*FF)     // 32768 facts
#define NNODE (BB*SS)  // 8192 (b,s) rows
#define FPB 32         // facts per msg block (64 messages)

typedef short  short8 __attribute__((ext_vector_type(8)));
typedef float  f32x4  __attribute__((ext_vector_type(4)));

__device__ __forceinline__ ushort f2bf(float x) {
    uint u = __float_as_uint(x);
    uint r = (u + 0x7fffu + ((u >> 16) & 1u)) >> 16;
    return (ushort)r;
}
__device__ __forceinline__ float bf2f(uint lo16) {
    return __uint_as_float(lo16 << 16);
}

// gelu(x) = 0.5x(1+erf(x/sqrt2)); erf via A&S 7.1.26, |err|<=1.5e-7, branchless.
__device__ __forceinline__ float gelu_fast(float x) {
    const float z = fabsf(x) * 0.70710678118654752440f;
    const float t = __builtin_amdgcn_rcpf(__builtin_fmaf(0.3275911f, z, 1.0f));
    float p = 1.061405429f;
    p = __builtin_fmaf(p, t, -1.453152027f);
    p = __builtin_fmaf(p, t, 1.421413741f);
    p = __builtin_fmaf(p, t, -0.284496736f);
    p = __builtin_fmaf(p, t, 0.254829592f);
    p *= t;
    const float e = __expf(-z * z);
    const float erfv = __builtin_fmaf(-p, e, 1.0f);   // erf(|x|/sqrt2)
    return 0.5f * x * (1.0f + copysignf(erfv, x));
}

__device__ __forceinline__ void pk_add_bf16(ushort* ap, uint packed) {
    asm volatile("global_atomic_pk_add_bf16 %0, %1, off"
                 :: "v"((unsigned long long)(uintptr_t)ap), "v"(packed) : "memory");
}

// ---------------------------------------------------------------------------
// Prep: bf16 embeddings; bf16 w1T[256][384], w2T[128][256].
// ---------------------------------------------------------------------------
#define N_POS   (SS*DD)
#define N_PRED_ (14*DD)
#define N_W1    (384*256)
#define N_W2    (256*128)
#define N_PREP  (N_POS + N_PRED_ + N_W1 + N_W2)

__global__ __launch_bounds__(256) void prep_kernel(
    const float* __restrict__ pos, const float* __restrict__ pred,
    const float* __restrict__ w1,  const float* __restrict__ w2,
    ushort* __restrict__ pos_bf, ushort* __restrict__ pred_bf,
    ushort* __restrict__ w1T,    ushort* __restrict__ w2T)
{
    int i = blockIdx.x * 256 + threadIdx.x;
    if (i < N_POS) { pos_bf[i] = f2bf(pos[i]); return; }
    i -= N_POS;
    if (i < N_PRED_) { pred_bf[i] = f2bf(pred[i]); return; }
    i -= N_PRED_;
    if (i < N_W1) { int k = i >> 8, n = i & 255; w1T[n*384 + k] = f2bf(w1[i]); return; }
    i -= N_W1;
    if (i < N_W2) { int k = i >> 7, d = i & 127; w2T[d*256 + k] = f2bf(w2[i]); return; }
}

// ---------------------------------------------------------------------------
// msg kernel (MFMA, swapped operands -> outputs indexed [n][m]/[d][m]).
// Epilogue: transpose message tile through LDS, then ROW-COALESCED packed
// bf16 atomics: one wave-instruction covers one message row (256 B, 2 lines).
// ---------------------------------------------------------------------------
__global__ __launch_bounds__(256) void msg_kernel(
    const int* __restrict__ a0, const int* __restrict__ a1,
    const int* __restrict__ pidx, const float* __restrict__ bidir,
    const ushort* __restrict__ pos_bf, const ushort* __restrict__ pred_bf,
    const ushort* __restrict__ w1T, const float* __restrict__ b1,
    const ushort* __restrict__ w2T, const float* __restrict__ b2,
    ushort* __restrict__ aggbf)
{
    __shared__ uint4 shm[2048];           // 32 KB union: xs / h1 / msg-tile

    const int tid = threadIdx.x;
    const int fbase = blockIdx.x * FPB;
    const int wid = tid >> 6, lane = tid & 63;
    const int lq = lane >> 4, lr = lane & 15;
    const int factL = lr >> 1, par = lr & 1;

    // ---- stage gathered inputs (bf16, 16B units, XOR-swizzled by fact&7) ----
    #pragma unroll
    for (int it = 0; it < 6; ++it) {
        const int U = tid + it * 256;
        const int f = U / 48, u = U - 48 * f;
        const int seg = u >> 4, du = u & 15;
        const int g = fbase + f;
        const int row = (seg == 0) ? a0[g] : ((seg == 1) ? pidx[g] : a1[g]);
        const uint4* src = (const uint4*)(((seg == 1) ? pred_bf : pos_bf) + row * DD) + du;
        shm[f * 48 + (u ^ (f & 7))] = *src;
    }
    __syncthreads();

    // ---- GEMM1: D1[n][m], acc[nf][mf] ----
    f32x4 acc[4][4];
    #pragma unroll
    for (int nf = 0; nf < 4; ++nf)
        #pragma unroll
        for (int mf = 0; mf < 4; ++mf) acc[nf][mf] = (f32x4)0.0f;

    for (int ks = 0; ks < 12; ++ks) {
        const int k_el = ks * 32 + lq * 8;
        const int seg = ks >> 2;
        const int kp = k_el + (par ? (seg == 0 ? 256 : (seg == 2 ? -256 : 0)) : 0);
        const int uq = (kp >> 3) ^ factL;
        short8 xfrag[4];
        #pragma unroll
        for (int mf = 0; mf < 4; ++mf)
            xfrag[mf] = *(const short8*)&shm[(mf * 8 + factL) * 48 + uq];
        short8 wfrag[4];
        #pragma unroll
        for (int nf = 0; nf < 4; ++nf)
            wfrag[nf] = *(const short8*)(w1T + (wid * 64 + nf * 16 + lr) * 384 + k_el);
        #pragma unroll
        for (int nf = 0; nf < 4; ++nf)
            #pragma unroll
            for (int mf = 0; mf < 4; ++mf)
                acc[nf][mf] = __builtin_amdgcn_mfma_f32_16x16x32_bf16(wfrag[nf], xfrag[mf], acc[nf][mf], 0, 0, 0);
    }
    __syncthreads();   // xs dead; reuse LDS as h1[64][256] bf16 (swizzled)

    // ---- bias + gelu + packed h1 store (ds_write_b64) ----
    #pragma unroll
    for (int nf = 0; nf < 4; ++nf) {
        const float4 bj = *(const float4*)(b1 + wid * 64 + nf * 16 + lq * 4);
        #pragma unroll
        for (int mf = 0; mf < 4; ++mf) {
            const int m = mf * 16 + lr;
            uint2 t;
            t.x = (uint)f2bf(gelu_fast(acc[nf][mf][0] + bj.x)) |
                  ((uint)f2bf(gelu_fast(acc[nf][mf][1] + bj.y)) << 16);
            t.y = (uint)f2bf(gelu_fast(acc[nf][mf][2] + bj.z)) |
                  ((uint)f2bf(gelu_fast(acc[nf][mf][3] + bj.w)) << 16);
            const int col = wid * 128 + nf * 32 + lq * 8;   // byte col
            const int byteoff = m * 512 + (((col >> 4) ^ (m & 15)) << 4) + (col & 15);
            *(uint2*)((char*)shm + byteoff) = t;
        }
    }
    __syncthreads();

    // ---- GEMM2: D2[d][m], acc2[nf][mf] ----
    f32x4 acc2[2][4];
    #pragma unroll
    for (int nf = 0; nf < 2; ++nf)
        #pragma unroll
        for (int mf = 0; mf < 4; ++mf) acc2[nf][mf] = (f32x4)0.0f;

    for (int ks = 0; ks < 8; ++ks) {
        short8 hfrag[4];
        #pragma unroll
        for (int mf = 0; mf < 4; ++mf) {
            const int m = mf * 16 + lr;
            hfrag[mf] = *(const short8*)((char*)shm + m * 512 + ((((ks * 4 + lq)) ^ (m & 15)) << 4));
        }
        short8 w2frag[2];
        #pragma unroll
        for (int nf = 0; nf < 2; ++nf)
            w2frag[nf] = *(const short8*)(w2T + (wid * 32 + nf * 16 + lr) * 256 + ks * 32 + lq * 8);
        #pragma unroll
        for (int nf = 0; nf < 2; ++nf)
            #pragma unroll
            for (int mf = 0; mf < 4; ++mf)
                acc2[nf][mf] = __builtin_amdgcn_mfma_f32_16x16x32_bf16(w2frag[nf], hfrag[mf], acc2[nf][mf], 0, 0, 0);
    }
    __syncthreads();   // h1 dead; reuse LDS as msg[64 rows][256 B] (8B-swizzled)

    // ---- write message tile to LDS (bias + bidir applied) ----
    {
        float wgt_[4];
        #pragma unroll
        for (int mf = 0; mf < 4; ++mf) {
            const int g = fbase + mf * 8 + factL;
            wgt_[mf] = par ? bidir[g] : 1.0f;
        }
        #pragma unroll
        for (int nf = 0; nf < 2; ++nf) {
            const float4 bd = *(const float4*)(b2 + wid * 32 + nf * 16 + lq * 4);
            const int d0 = wid * 32 + nf * 16 + lq * 4;
            #pragma unroll
            for (int mf = 0; mf < 4; ++mf) {
                const int m = mf * 16 + lr;
                const float w = wgt_[mf];
                uint2 t;
                t.x = (uint)f2bf((acc2[nf][mf][0] + bd.x) * w) |
                      ((uint)f2bf((acc2[nf][mf][1] + bd.y) * w) << 16);
                t.y = (uint)f2bf((acc2[nf][mf][2] + bd.z) * w) |
                      ((uint)f2bf((acc2[nf][mf][3] + bd.w) * w) << 16);
                const int byteoff = m * 256 + ((d0 * 2) ^ ((m & 15) << 3));
                *(uint2*)((char*)shm + byteoff) = t;
            }
        }
    }
    __syncthreads();

    // ---- row-coalesced atomic scatter: wave handles rows wid*16..+15 ----
    {
        const int bidx = fbase >> 12;
        ushort* aggb = aggbf + ((size_t)bidx << 10) * DD;
        #pragma unroll
        for (int r = 0; r < 16; ++r) {
            const int m = wid * 16 + r;
            const int f = m >> 1, p = m & 1;
            const float w = p ? bidir[fbase + f] : 1.0f;   // wave-uniform
            if (w != 0.0f) {
                const int node = p ? a0[fbase + f] : a1[fbase + f];
                const uint val = *(const uint*)((char*)shm + m * 256 + ((lane * 4) ^ ((m & 15) << 3)));
                pk_add_bf16(aggb + (size_t)node * DD + lane * 2, val);
            }
        }
    }
}

// ---------------------------------------------------------------------------
// h = pos_emb + aggbf -> LayerNorm -> pooled sums per (b,d).
// ---------------------------------------------------------------------------
#define NPW 4
__global__ __launch_bounds__(256) void ln_pool_kernel(
    const float* __restrict__ pos_emb, const ushort* __restrict__ aggbf,
    const float* __restrict__ ln_g, const float* __restrict__ ln_b,
    float* __restrict__ pooled)
{
    const int wave = threadIdx.x >> 6, lane = threadIdx.x & 63;
    const int nid0 = blockIdx.x * (4 * NPW) + wave * NPW;
    const int b = nid0 >> 10;
    const float2 g2  = *(const float2*)(ln_g + 2 * lane);
    const float2 bb2 = *(const float2*)(ln_b + 2 * lane);
    float p0 = 0.0f, p1 = 0.0f;

    for (int i = 0; i < NPW; ++i) {
        const int nid = nid0 + i;
        const int s = nid & (SS - 1);
        float2 h = *(const float2*)(pos_emb + s * DD + 2 * lane);
        const uint u = *(const uint*)(aggbf + (size_t)nid * DD + 2 * lane);
        h.x += bf2f(u & 0xffffu);
        h.y += bf2f(u >> 16);

        float sum = h.x + h.y;
        #pragma unroll
        for (int o = 32; o > 0; o >>= 1) sum += __shfl_xor(sum, o);
        const float mu = sum * (1.0f / 128.0f);
        const float d0 = h.x - mu, d1 = h.y - mu;
        float sq = d0 * d0 + d1 * d1;
        #pragma unroll
        for (int o = 32; o > 0; o >>= 1) sq += __shfl_xor(sq, o);
        const float rstd = rsqrtf(sq * (1.0f / 128.0f) + 1e-5f);
        p0 += d0 * rstd * g2.x + bb2.x;
        p1 += d1 * rstd * g2.y + bb2.y;
    }

    __shared__ float red[4][128];
    red[wave][2 * lane]     = p0;
    red[wave][2 * lane + 1] = p1;
    __syncthreads();
    if (threadIdx.x < 128) {
        const float v = red[0][threadIdx.x] + red[1][threadIdx.x]
                      + red[2][threadIdx.x] + red[3][threadIdx.x];
        atomicAdd(&pooled[b * DD + threadIdx.x], v);
    }
}

// ---------------------------------------------------------------------------
// Latent head
// ---------------------------------------------------------------------------
__global__ __launch_bounds__(256) void head_kernel(
    const float* __restrict__ pooled,
    const float* __restrict__ lw1, const float* __restrict__ lb1,
    const float* __restrict__ lw2, const float* __restrict__ lb2,
    float* __restrict__ out)
{
    const int b = blockIdx.x;
    const int j = threadIdx.x;
    __shared__ float p[128];
    __shared__ float t1[256];
    if (j < 128) p[j] = pooled[b*DD + j] * (1.0f / (float)SS);
    __syncthreads();
    float acc = lb1[j];
    for (int k = 0; k < 128; ++k) acc += p[k] * lw1[k*256 + j];
    t1[j] = gelu_fast(acc);
    __syncthreads();
    float acc2 = lb2[j];
    for (int k = 0; k < 256; ++k) acc2 += t1[k] * lw2[k*256 + j];
    out[b*DLL + j] = acc2;
}

extern "C" void kernel_launch(void* const* d_in, const int* in_sizes, int n_in,
                              void* d_out, int out_size, void* d_ws, size_t ws_size,
                              hipStream_t stream) {
    const int*   a0       = (const int*)d_in[0];
    const int*   a1       = (const int*)d_in[1];
    const int*   pidx     = (const int*)d_in[2];
    const float* bidir    = (const float*)d_in[3];
    const float* pos_emb  = (const float*)d_in[4];
    const float* pred_emb = (const float*)d_in[5];
    const float* w1       = (const float*)d_in[6];
    const float* b1       = (const float*)d_in[7];
    const float* w2       = (const float*)d_in[8];
    const float* b2       = (const float*)d_in[9];
    const float* ln_g     = (const float*)d_in[10];
    const float* ln_b     = (const float*)d_in[11];
    const float* lw1      = (const float*)d_in[12];
    const float* lb1      = (const float*)d_in[13];
    const float* lw2      = (const float*)d_in[14];
    const float* lb2      = (const float*)d_in[15];

    char* ws = (char*)d_ws;
    const size_t O_AGG  = 0;                 // NNODE*128 bf16 = 2 MB
    const size_t O_POOL = 2097152;           // 4 KB fp32
    const size_t O_PBF  = O_POOL + 4096;     // 256 KB
    const size_t O_PRBF = O_PBF + 262144;    // 3.5 KB
    const size_t O_W1T  = O_PRBF + 3584;     // 192 KB
    const size_t O_W2T  = O_W1T + 196608;    // 64 KB

    ushort* aggbf  = (ushort*)(ws + O_AGG);
    float*  pooled = (float*)(ws + O_POOL);
    ushort* pos_bf = (ushort*)(ws + O_PBF);
    ushort* pred_bf= (ushort*)(ws + O_PRBF);
    ushort* w1T    = (ushort*)(ws + O_W1T);
    ushort* w2T    = (ushort*)(ws + O_W2T);

    hipMemsetAsync(ws, 0, O_POOL + 4096, stream);   // aggbf (bf16 zeros) + pooled
    prep_kernel<<<(N_PREP + 255)/256, 256, 0, stream>>>(
        pos_emb, pred_emb, w1, w2, pos_bf, pred_bf, w1T, w2T);
    msg_kernel<<<NF/FPB, 256, 0, stream>>>(a0, a1, pidx, bidir,
        pos_bf, pred_bf, w1T, b1, w2T, b2, aggbf);
    ln_pool_kernel<<<NNODE/(4*NPW), 256, 0, stream>>>(
        pos_emb, aggbf, ln_g, ln_b, pooled);
    head_kernel<<<BB, 256, 0, stream>>>(pooled, lw1, lb1, lw2, lb2, (float*)d_out);
}